// Round 6
// baseline (180.212 us; speedup 1.0000x reference)
//
#include <hip/hip_runtime.h>
#include <hip/hip_bf16.h>

#define SENTINEL 24635

using bf16x8  = __attribute__((ext_vector_type(8))) __bf16;
using bf16x2  = __attribute__((ext_vector_type(2))) __bf16;
using floatx4 = __attribute__((ext_vector_type(4))) float;

__device__ inline bf16x8 cvt8(float4 a, float4 b) {
  bf16x8 v;
  v[0] = (__bf16)a.x; v[1] = (__bf16)a.y; v[2] = (__bf16)a.z; v[3] = (__bf16)a.w;
  v[4] = (__bf16)b.x; v[5] = (__bf16)b.y; v[6] = (__bf16)b.z; v[7] = (__bf16)b.w;
  return v;
}

// async global->LDS, 16 B per lane. LDS dest = wave-uniform base + lane*16.
__device__ inline void gll16(const __bf16* g, __bf16* l) {
  __builtin_amdgcn_global_load_lds(
      (const __attribute__((address_space(1))) unsigned int*)g,
      (__attribute__((address_space(3))) unsigned int*)l, 16, 0, 0);
}

// ---------------------------------------------------------------------------
// Prep: f32->bf16 convert of ctx/W1/W2/W3 (blocks 0..2655, 8 elems/thread)
// fused with pool (blocks 2656..3679): user_n[b] = bf16 masked mean of
// ent_embs[ent_list[b,:cnt]]; cnt = first-SENTINEL prefix; cnt==0 -> sentinel
// row. Pool: wave per row, batches of 10 independent gathers.
// ---------------------------------------------------------------------------
__global__ __launch_bounds__(256) void prep_kernel(
    const float* __restrict__ s0, __bf16* __restrict__ d0,
    const float* __restrict__ s1, __bf16* __restrict__ d1,
    const float* __restrict__ s2, __bf16* __restrict__ d2,
    const float* __restrict__ s3, __bf16* __restrict__ d3,
    const float* __restrict__ ent, const int* __restrict__ ent_list,
    __bf16* __restrict__ user_n) {
  if (blockIdx.x < 2656) {
    // sizes in 8-elem units: ctx 524288, W1 98304, W2 49152, W3 8192
    int g = blockIdx.x * 256 + threadIdx.x;
    const float* s; __bf16* d; int i;
    if (g < 524288)               { s = s0; d = d0; i = g; }
    else if (g < 622592)          { s = s1; d = d1; i = g - 524288; }
    else if (g < 671744)          { s = s2; d = d2; i = g - 622592; }
    else if (g < 679936 - 8192)   { s = s3; d = d3; i = g - 671744; }
    else return;
    i *= 8;
    float4 a = *(const float4*)(s + i);
    float4 b = *(const float4*)(s + i + 4);
    *(bf16x8*)(d + i) = cvt8(a, b);
    return;
  }
  const int b = (blockIdx.x - 2656) * 4 + (threadIdx.x >> 6);
  const int lane = threadIdx.x & 63;
  int myidx = (lane < 50) ? ent_list[b * 50 + lane] : 0;
  unsigned long long m = __ballot(lane < 50 && myidx == SENTINEL);
  const int cnt = (m == 0) ? 50 : (int)__builtin_ctzll(m);

  float sx = 0.f, sy = 0.f;
  for (int l0 = 0; l0 < 50; l0 += 10) {
    if (l0 >= cnt) break;  // wave-uniform
    float2 e[10];
#pragma unroll
    for (int j = 0; j < 10; ++j) {
      int idx = __shfl(myidx, l0 + j);
      e[j] = *(const float2*)(ent + (size_t)idx * 128 + lane * 2);
    }
#pragma unroll
    for (int j = 0; j < 10; ++j) {
      if (l0 + j < cnt) { sx += e[j].x; sy += e[j].y; }
    }
  }
  float vx, vy;
  if (cnt == 0) {
    float2 e = *(const float2*)(ent + (size_t)SENTINEL * 128 + lane * 2);
    vx = e.x; vy = e.y;
  } else {
    float inv = 1.f / (float)cnt;
    vx = sx * inv; vy = sy * inv;
  }
  bf16x2 o; o[0] = (__bf16)vx; o[1] = (__bf16)vy;
  *(bf16x2*)(user_n + (size_t)b * 128 + lane * 2) = o;
}

// ---------------------------------------------------------------------------
// Transpose user_n [4096][128] bf16 -> user_t [128][4096] bf16 via LDS tiles.
// ---------------------------------------------------------------------------
__global__ __launch_bounds__(256) void transpose_kernel(const __bf16* __restrict__ in,
                                                        __bf16* __restrict__ out) {
  __shared__ __bf16 T[64][72];
  const int r0 = blockIdx.x * 64;
  const int c0 = blockIdx.y * 64;
  const int tid = threadIdx.x;
#pragma unroll
  for (int p = 0; p < 2; ++p) {
    int r = (tid >> 3) + p * 32;
    int c = (tid & 7) * 8;
    *(bf16x8*)&T[r][c] = *(const bf16x8*)(in + (size_t)(r0 + r) * 128 + c0 + c);
  }
  __syncthreads();
#pragma unroll
  for (int p = 0; p < 2; ++p) {
    int c = (tid >> 3) + p * 32;
    int r = (tid & 7) * 8;
    bf16x8 v;
#pragma unroll
    for (int j = 0; j < 8; ++j) v[j] = T[r + j][c];
    *(bf16x8*)(out + (size_t)(c0 + c) * 4096 + r0 + r) = v;
  }
}

// ---------------------------------------------------------------------------
// Single-pass GEMM: C[m][n] = bf16( act( sum_k A[m][k]*W[n][k] ) )
// A,W,C bf16 row-major (K contiguous). Block tile (WR*MT*16) x (WC*NT*16),
// BK=64, 256 threads = 4 waves arranged WR x WC.
// LDS: two K-slabs of 32 (m97 layout: unpadded 64 B rows, gll16 chunks of
// 16 rows). Requires M%BM==0, N%BN==0, K%64==0.
// ---------------------------------------------------------------------------
template <int WR, int WC, int MT, int NT, int RELU>
__global__ __launch_bounds__(256) void gemm_bt(const __bf16* __restrict__ A,
                                               const __bf16* __restrict__ W,
                                               __bf16* __restrict__ C,
                                               int M, int N, int K) {
  constexpr int BM = WR * MT * 16;
  constexpr int BN = WC * NT * 16;
  __shared__ __bf16 As[2][BM][32];
  __shared__ __bf16 Bs[2][BN][32];
  const int bn0 = blockIdx.x * BN;
  const int bm0 = blockIdx.y * BM;
  const int tid  = threadIdx.x;
  const int w    = tid >> 6;
  const int lane = tid & 63;
  const int quad = lane >> 4;
  const int l16  = lane & 15;
  const int wr   = w / WC;
  const int wc   = w % WC;
  const int lrow = lane >> 2;        // 0..15 row within 1 KB chunk
  const int lcol = (lane & 3) * 8;   // bf16 col within 32-wide slab row

  floatx4 acc[MT][NT];
#pragma unroll
  for (int mt = 0; mt < MT; ++mt)
#pragma unroll
    for (int nt = 0; nt < NT; ++nt) acc[mt][nt] = (floatx4){0.f, 0.f, 0.f, 0.f};

  constexpr int nAc = 2 * (BM / 16);  // chunks: slab-major
  constexpr int nBc = 2 * (BN / 16);
  for (int k0 = 0; k0 < K; k0 += 64) {
    __syncthreads();
#pragma unroll
    for (int c = w; c < nAc; c += 4) {
      int s = c / (BM / 16);
      int r = (c % (BM / 16)) * 16;
      gll16(A + (size_t)(bm0 + r + lrow) * K + k0 + s * 32 + lcol, &As[s][r][0]);
    }
#pragma unroll
    for (int c = w; c < nBc; c += 4) {
      int s = c / (BN / 16);
      int r = (c % (BN / 16)) * 16;
      gll16(W + (size_t)(bn0 + r + lrow) * K + k0 + s * 32 + lcol, &Bs[s][r][0]);
    }
    __syncthreads();
#pragma unroll
    for (int s = 0; s < 2; ++s) {
      bf16x8 af[MT], bfr[NT];
#pragma unroll
      for (int mt = 0; mt < MT; ++mt)
        af[mt] = *(const bf16x8*)&As[s][wr * (MT * 16) + mt * 16 + l16][quad * 8];
#pragma unroll
      for (int nt = 0; nt < NT; ++nt)
        bfr[nt] = *(const bf16x8*)&Bs[s][wc * (NT * 16) + nt * 16 + l16][quad * 8];
#pragma unroll
      for (int mt = 0; mt < MT; ++mt)
#pragma unroll
        for (int nt = 0; nt < NT; ++nt)
          acc[mt][nt] =
              __builtin_amdgcn_mfma_f32_16x16x32_bf16(af[mt], bfr[nt], acc[mt][nt], 0, 0, 0);
    }
  }

#pragma unroll
  for (int mt = 0; mt < MT; ++mt) {
    const int row0 = bm0 + wr * (MT * 16) + mt * 16 + quad * 4;
#pragma unroll
    for (int nt = 0; nt < NT; ++nt) {
      const int col = bn0 + wc * (NT * 16) + nt * 16 + l16;
#pragma unroll
      for (int r = 0; r < 4; ++r) {
        float v = acc[mt][nt][r];
        if (RELU) v = fmaxf(v, 0.f);
        C[(size_t)(row0 + r) * N + col] = (__bf16)v;
      }
    }
  }
}

// ---------------------------------------------------------------------------
// Flash attention, ZERO-barrier K-loop. No max-subtraction (|scores|~1e-2).
//   O_part[split] = sum_chunks exp(Q Uc^T * scale) @ Uc ; l_part = row sums.
// U fragments (both layouts) read DIRECTLY from global: user_n/user_t are
// 1 MB each, each chunk's 32 KB working set is L1-resident and shared by the
// block's 4 waves -> no LDS staging, no __syncthreads anywhere in the loop.
// Only the per-wave P C-layout -> A-layout transpose uses LDS (wave-private,
// compiler lgkmcnt ordering suffices). 128 q-rows/block (wave owns 32);
// grid (32 q-tiles, 16 key-splits) = 512 blocks. O_part stored bf16.
// ---------------------------------------------------------------------------
__global__ __launch_bounds__(256) void flash_attn(const __bf16* __restrict__ Q,
                                                  const __bf16* __restrict__ Un_g,
                                                  const __bf16* __restrict__ Ut_g,
                                                  __bf16* __restrict__ O_part,
                                                  float* __restrict__ l_part) {
  __shared__ __bf16 Ps[4][32][72];  // per-wave P [qrow 0..31][key], wave-private
  const int tid  = threadIdx.x;
  const int w    = tid >> 6;
  const int lane = tid & 63;
  const int quad = lane >> 4;
  const int l16  = lane & 15;
  const int qrow0 = blockIdx.x * 128;
  const int split = blockIdx.y;
  const float scale = 0.08838834764831845f;  // 1/sqrt(128)

  bf16x8 aq[2][4];
#pragma unroll
  for (int mt = 0; mt < 2; ++mt)
#pragma unroll
    for (int c = 0; c < 4; ++c)
      aq[mt][c] = *(const bf16x8*)(Q + (size_t)(qrow0 + w * 32 + mt * 16 + l16) * 128 +
                                   c * 32 + quad * 8);

  floatx4 o[2][8];
#pragma unroll
  for (int mt = 0; mt < 2; ++mt)
#pragma unroll
    for (int t = 0; t < 8; ++t) o[mt][t] = (floatx4){0.f, 0.f, 0.f, 0.f};
  float lsum[2][4] = {{0.f, 0.f, 0.f, 0.f}, {0.f, 0.f, 0.f, 0.f}};

  for (int chunk = 0; chunk < 4; ++chunk) {
    const int key0 = (split * 4 + chunk) * 64;

    // S = Q Uc^T; B-fragments straight from global (L1-shared across waves).
#pragma unroll
    for (int t = 0; t < 4; ++t) {
      bf16x8 bk[4];
#pragma unroll
      for (int c = 0; c < 4; ++c)
        bk[c] = *(const bf16x8*)(Un_g + (size_t)(key0 + t * 16 + l16) * 128 +
                                 c * 32 + quad * 8);
      floatx4 s0 = (floatx4){0.f, 0.f, 0.f, 0.f};
      floatx4 s1 = (floatx4){0.f, 0.f, 0.f, 0.f};
#pragma unroll
      for (int c = 0; c < 4; ++c) {
        s0 = __builtin_amdgcn_mfma_f32_16x16x32_bf16(aq[0][c], bk[c], s0, 0, 0, 0);
        s1 = __builtin_amdgcn_mfma_f32_16x16x32_bf16(aq[1][c], bk[c], s1, 0, 0, 0);
      }
#pragma unroll
      for (int r = 0; r < 4; ++r) {
        float p0 = __expf(s0[r] * scale);
        float p1 = __expf(s1[r] * scale);
        lsum[0][r] += p0;
        lsum[1][r] += p1;
        Ps[w][quad * 4 + r][t * 16 + l16] = (__bf16)p0;
        Ps[w][16 + quad * 4 + r][t * 16 + l16] = (__bf16)p1;
      }
    }

    // O += P @ Uc ; P via wave-private LDS transpose, V rows from global.
#pragma unroll
    for (int c2 = 0; c2 < 2; ++c2) {
      bf16x8 ap0 = *(const bf16x8*)&Ps[w][l16][c2 * 32 + quad * 8];
      bf16x8 ap1 = *(const bf16x8*)&Ps[w][16 + l16][c2 * 32 + quad * 8];
#pragma unroll
      for (int dt = 0; dt < 8; ++dt) {
        bf16x8 bv = *(const bf16x8*)(Ut_g + (size_t)(dt * 16 + l16) * 4096 +
                                     key0 + c2 * 32 + quad * 8);
        o[0][dt] = __builtin_amdgcn_mfma_f32_16x16x32_bf16(ap0, bv, o[0][dt], 0, 0, 0);
        o[1][dt] = __builtin_amdgcn_mfma_f32_16x16x32_bf16(ap1, bv, o[1][dt], 0, 0, 0);
      }
    }
  }

  // Row sums: reduce over the 16 key-columns held across l16.
#pragma unroll
  for (int mt = 0; mt < 2; ++mt)
#pragma unroll
    for (int r = 0; r < 4; ++r) {
      float v = lsum[mt][r];
      v += __shfl_xor(v, 1);
      v += __shfl_xor(v, 2);
      v += __shfl_xor(v, 4);
      v += __shfl_xor(v, 8);
      lsum[mt][r] = v;
    }

  __bf16* Ob = O_part + (size_t)split * 4096 * 128;
#pragma unroll
  for (int mt = 0; mt < 2; ++mt) {
    const int row0 = qrow0 + w * 32 + mt * 16 + quad * 4;
#pragma unroll
    for (int dt = 0; dt < 8; ++dt) {
#pragma unroll
      for (int r = 0; r < 4; ++r) {
        Ob[(size_t)(row0 + r) * 128 + dt * 16 + l16] = (__bf16)o[mt][dt][r];
      }
    }
    if (l16 == 0) {
#pragma unroll
      for (int r = 0; r < 4; ++r) l_part[split * 4096 + row0 + r] = lsum[mt][r];
    }
  }
}

// ---------------------------------------------------------------------------
// Combine 16 key-splits: out = (sum_s O_s) / (sum_s l_s). 8 elems/thread.
// ---------------------------------------------------------------------------
__global__ __launch_bounds__(256) void combine_kernel(const __bf16* __restrict__ O_part,
                                                      const float* __restrict__ l_part,
                                                      float* __restrict__ out) {
  const int i = (blockIdx.x * 256 + threadIdx.x) * 8;  // 0 .. 524287 step 8
  const int row = i >> 7;
  float num[8] = {0.f, 0.f, 0.f, 0.f, 0.f, 0.f, 0.f, 0.f};
  float den = 0.f;
#pragma unroll
  for (int s = 0; s < 16; ++s) {
    bf16x8 v = *(const bf16x8*)(O_part + (size_t)s * 524288 + i);
#pragma unroll
    for (int j = 0; j < 8; ++j) num[j] += (float)v[j];
    den += l_part[s * 4096 + row];
  }
  float inv = 1.f / den;
  float4 r0 = {num[0] * inv, num[1] * inv, num[2] * inv, num[3] * inv};
  float4 r1 = {num[4] * inv, num[5] * inv, num[6] * inv, num[7] * inv};
  *(float4*)(out + i) = r0;
  *(float4*)(out + i + 4) = r1;
}

extern "C" void kernel_launch(void* const* d_in, const int* in_sizes, int n_in,
                              void* d_out, int out_size, void* d_ws, size_t ws_size,
                              hipStream_t stream) {
  (void)in_sizes; (void)n_in; (void)out_size; (void)ws_size;
  const float* ctx      = (const float*)d_in[0];  // [4096,1024]
  const float* ent_embs = (const float*)d_in[1];  // [24636,128]
  const float* W1       = (const float*)d_in[2];  // [768,1024]
  const float* W2       = (const float*)d_in[3];  // [512,768]
  const float* W3       = (const float*)d_in[4];  // [128,512]
  const int*   ent_list = (const int*)d_in[5];    // [4096,50]
  float* out = (float*)d_out;

  // ws layout; peak use 41 MB (ws is 256 MB).
  char* base = (char*)d_ws;
  __bf16* user_n = (__bf16*)(base);                       // 1 MB
  __bf16* user_t = (__bf16*)(base + (1ull << 20));        // 1 MB
  __bf16* qb     = (__bf16*)(base + (2ull << 20));        // 1 MB
  float*  l_part = (float*)(base + (3ull << 20));         // 256 KB
  __bf16* ctxb   = (__bf16*)(base + (4ull << 20));        // 8 MB
  __bf16* W1b    = (__bf16*)(base + (12ull << 20));       // 1.5 MB
  __bf16* W2b    = (__bf16*)(base + 14155776ull);         // 13.5 MB, 0.75 MB
  __bf16* W3b    = (__bf16*)(base + 14942208ull);         // 14.25 MB, 128 KB
  __bf16* x1b    = (__bf16*)(base + (15ull << 20));       // 6 MB
  __bf16* x2b    = (__bf16*)(base + (21ull << 20));       // 4 MB
  __bf16* O_part = (__bf16*)(base + (25ull << 20));       // 16 MB (bf16 x 16 splits)

  prep_kernel<<<3680, 256, 0, stream>>>(ctx, ctxb, W1, W1b, W2, W2b, W3, W3b,
                                        ent_embs, ent_list, user_n);
  transpose_kernel<<<dim3(64, 2), 256, 0, stream>>>(user_n, user_t);

  // MLP: 128x96 / 128x64 / 32x64 tiles, relu+cvt fused in epilogue.
  gemm_bt<4, 1, 2, 6, 1><<<dim3(8, 32), 256, 0, stream>>>(ctxb, W1b, x1b, 4096, 768, 1024);
  gemm_bt<4, 1, 2, 4, 1><<<dim3(8, 32), 256, 0, stream>>>(x1b, W2b, x2b, 4096, 512, 768);
  gemm_bt<2, 2, 1, 2, 0><<<dim3(2, 128), 256, 0, stream>>>(x2b, W3b, qb, 4096, 128, 512);

  flash_attn<<<dim3(32, 16), 256, 0, stream>>>(qb, user_n, user_t, O_part, l_part);
  combine_kernel<<<256, 256, 0, stream>>>(O_part, l_part, out);
}

// Round 7
// 171.438 us; speedup vs baseline: 1.0512x; 1.0512x over previous
//
#include <hip/hip_runtime.h>
#include <hip/hip_bf16.h>

#define SENTINEL 24635

using bf16x8  = __attribute__((ext_vector_type(8))) __bf16;
using bf16x2  = __attribute__((ext_vector_type(2))) __bf16;
using floatx4 = __attribute__((ext_vector_type(4))) float;

__device__ inline bf16x8 cvt8(float4 a, float4 b) {
  bf16x8 v;
  v[0] = (__bf16)a.x; v[1] = (__bf16)a.y; v[2] = (__bf16)a.z; v[3] = (__bf16)a.w;
  v[4] = (__bf16)b.x; v[5] = (__bf16)b.y; v[6] = (__bf16)b.z; v[7] = (__bf16)b.w;
  return v;
}

// async global->LDS, 16 B per lane. LDS dest = wave-uniform base + lane*16.
__device__ inline void gll16(const __bf16* g, __bf16* l) {
  __builtin_amdgcn_global_load_lds(
      (const __attribute__((address_space(1))) unsigned int*)g,
      (__attribute__((address_space(3))) unsigned int*)l, 16, 0, 0);
}

// ---------------------------------------------------------------------------
// Prep: f32->bf16 convert of ctx/W1/W2/W3 (blocks 0..2655, 8 elems/thread)
// fused with pool (blocks 2656..3679): user_n[b] = bf16 masked mean of
// ent_embs[ent_list[b,:cnt]]; cnt = first-SENTINEL prefix; cnt==0 -> sentinel.
// ---------------------------------------------------------------------------
__global__ __launch_bounds__(256) void prep_kernel(
    const float* __restrict__ s0, __bf16* __restrict__ d0,
    const float* __restrict__ s1, __bf16* __restrict__ d1,
    const float* __restrict__ s2, __bf16* __restrict__ d2,
    const float* __restrict__ s3, __bf16* __restrict__ d3,
    const float* __restrict__ ent, const int* __restrict__ ent_list,
    __bf16* __restrict__ user_n) {
  if (blockIdx.x < 2656) {
    // sizes in 8-elem units: ctx 524288, W1 98304, W2 49152, W3 8192
    int g = blockIdx.x * 256 + threadIdx.x;
    const float* s; __bf16* d; int i;
    if (g < 524288)               { s = s0; d = d0; i = g; }
    else if (g < 622592)          { s = s1; d = d1; i = g - 524288; }
    else if (g < 671744)          { s = s2; d = d2; i = g - 622592; }
    else if (g < 679936)          { s = s3; d = d3; i = g - 671744; }
    else return;
    i *= 8;
    float4 a = *(const float4*)(s + i);
    float4 b = *(const float4*)(s + i + 4);
    *(bf16x8*)(d + i) = cvt8(a, b);
    return;
  }
  const int b = (blockIdx.x - 2656) * 4 + (threadIdx.x >> 6);
  const int lane = threadIdx.x & 63;
  int myidx = (lane < 50) ? ent_list[b * 50 + lane] : 0;
  unsigned long long m = __ballot(lane < 50 && myidx == SENTINEL);
  const int cnt = (m == 0) ? 50 : (int)__builtin_ctzll(m);

  float sx = 0.f, sy = 0.f;
  for (int l0 = 0; l0 < 50; l0 += 10) {
    if (l0 >= cnt) break;  // wave-uniform
    float2 e[10];
#pragma unroll
    for (int j = 0; j < 10; ++j) {
      int idx = __shfl(myidx, l0 + j);
      e[j] = *(const float2*)(ent + (size_t)idx * 128 + lane * 2);
    }
#pragma unroll
    for (int j = 0; j < 10; ++j) {
      if (l0 + j < cnt) { sx += e[j].x; sy += e[j].y; }
    }
  }
  float vx, vy;
  if (cnt == 0) {
    float2 e = *(const float2*)(ent + (size_t)SENTINEL * 128 + lane * 2);
    vx = e.x; vy = e.y;
  } else {
    float inv = 1.f / (float)cnt;
    vx = sx * inv; vy = sy * inv;
  }
  bf16x2 o; o[0] = (__bf16)vx; o[1] = (__bf16)vy;
  *(bf16x2*)(user_n + (size_t)b * 128 + lane * 2) = o;
}

// ---------------------------------------------------------------------------
// Transpose user_n [4096][128] bf16 -> user_t [128][4096] bf16 via LDS tiles.
// ---------------------------------------------------------------------------
__global__ __launch_bounds__(256) void transpose_kernel(const __bf16* __restrict__ in,
                                                        __bf16* __restrict__ out) {
  __shared__ __bf16 T[64][72];
  const int r0 = blockIdx.x * 64;
  const int c0 = blockIdx.y * 64;
  const int tid = threadIdx.x;
#pragma unroll
  for (int p = 0; p < 2; ++p) {
    int r = (tid >> 3) + p * 32;
    int c = (tid & 7) * 8;
    *(bf16x8*)&T[r][c] = *(const bf16x8*)(in + (size_t)(r0 + r) * 128 + c0 + c);
  }
  __syncthreads();
#pragma unroll
  for (int p = 0; p < 2; ++p) {
    int c = (tid >> 3) + p * 32;
    int r = (tid & 7) * 8;
    bf16x8 v;
#pragma unroll
    for (int j = 0; j < 8; ++j) v[j] = T[r + j][c];
    *(bf16x8*)(out + (size_t)(c0 + c) * 4096 + r0 + r) = v;
  }
}

// ---------------------------------------------------------------------------
// Single-pass GEMM: C[m][n] = bf16( act( sum_k A[m][k]*W[n][k] ) )
// A,W,C bf16 row-major (K contiguous). Block tile (WR*MT*16) x (WC*NT*16),
// BK=64, 256 threads = 4 waves arranged WR x WC. LDS: two K-slabs of 32
// (m97 layout: unpadded 64 B rows, gll16 chunks of 16 rows).
// ---------------------------------------------------------------------------
template <int WR, int WC, int MT, int NT, int RELU>
__global__ __launch_bounds__(256) void gemm_bt(const __bf16* __restrict__ A,
                                               const __bf16* __restrict__ W,
                                               __bf16* __restrict__ C,
                                               int M, int N, int K) {
  constexpr int BM = WR * MT * 16;
  constexpr int BN = WC * NT * 16;
  __shared__ __bf16 As[2][BM][32];
  __shared__ __bf16 Bs[2][BN][32];
  const int bn0 = blockIdx.x * BN;
  const int bm0 = blockIdx.y * BM;
  const int tid  = threadIdx.x;
  const int w    = tid >> 6;
  const int lane = tid & 63;
  const int quad = lane >> 4;
  const int l16  = lane & 15;
  const int wr   = w / WC;
  const int wc   = w % WC;
  const int lrow = lane >> 2;        // 0..15 row within 1 KB chunk
  const int lcol = (lane & 3) * 8;   // bf16 col within 32-wide slab row

  floatx4 acc[MT][NT];
#pragma unroll
  for (int mt = 0; mt < MT; ++mt)
#pragma unroll
    for (int nt = 0; nt < NT; ++nt) acc[mt][nt] = (floatx4){0.f, 0.f, 0.f, 0.f};

  constexpr int nAc = 2 * (BM / 16);  // chunks: slab-major
  constexpr int nBc = 2 * (BN / 16);
  for (int k0 = 0; k0 < K; k0 += 64) {
    __syncthreads();
#pragma unroll
    for (int c = w; c < nAc; c += 4) {
      int s = c / (BM / 16);
      int r = (c % (BM / 16)) * 16;
      gll16(A + (size_t)(bm0 + r + lrow) * K + k0 + s * 32 + lcol, &As[s][r][0]);
    }
#pragma unroll
    for (int c = w; c < nBc; c += 4) {
      int s = c / (BN / 16);
      int r = (c % (BN / 16)) * 16;
      gll16(W + (size_t)(bn0 + r + lrow) * K + k0 + s * 32 + lcol, &Bs[s][r][0]);
    }
    __syncthreads();
#pragma unroll
    for (int s = 0; s < 2; ++s) {
      bf16x8 af[MT], bfr[NT];
#pragma unroll
      for (int mt = 0; mt < MT; ++mt)
        af[mt] = *(const bf16x8*)&As[s][wr * (MT * 16) + mt * 16 + l16][quad * 8];
#pragma unroll
      for (int nt = 0; nt < NT; ++nt)
        bfr[nt] = *(const bf16x8*)&Bs[s][wc * (NT * 16) + nt * 16 + l16][quad * 8];
#pragma unroll
      for (int mt = 0; mt < MT; ++mt)
#pragma unroll
        for (int nt = 0; nt < NT; ++nt)
          acc[mt][nt] =
              __builtin_amdgcn_mfma_f32_16x16x32_bf16(af[mt], bfr[nt], acc[mt][nt], 0, 0, 0);
    }
  }

#pragma unroll
  for (int mt = 0; mt < MT; ++mt) {
    const int row0 = bm0 + wr * (MT * 16) + mt * 16 + quad * 4;
#pragma unroll
    for (int nt = 0; nt < NT; ++nt) {
      const int col = bn0 + wc * (NT * 16) + nt * 16 + l16;
#pragma unroll
      for (int r = 0; r < 4; ++r) {
        float v = acc[mt][nt][r];
        if (RELU) v = fmaxf(v, 0.f);
        C[(size_t)(row0 + r) * N + col] = (__bf16)v;
      }
    }
  }
}

// ---------------------------------------------------------------------------
// S-GEMM + exp: P[q][k] = bf16( exp( (Q . U^T) * scale ) ), K=128.
// 128x128 tiles, grid (32 key-tiles, 32 q-tiles) = 1024 blocks (4/CU).
// Fused epilogue: fp32 per-block row sums -> lp[row][64] (slot bx*2+wc),
// no atomics, deterministic. No max-subtraction: |scores| ~ 1e-2.
// ---------------------------------------------------------------------------
__global__ __launch_bounds__(256) void sgemm_exp(const __bf16* __restrict__ Q,
                                                 const __bf16* __restrict__ U,
                                                 __bf16* __restrict__ P,
                                                 float* __restrict__ lp) {
  __shared__ __bf16 As[2][128][32];
  __shared__ __bf16 Bs[2][128][32];
  const int bn0 = blockIdx.x * 128;
  const int bm0 = blockIdx.y * 128;
  const int tid  = threadIdx.x;
  const int w    = tid >> 6;
  const int lane = tid & 63;
  const int quad = lane >> 4;
  const int l16  = lane & 15;
  const int wr   = w >> 1;
  const int wc   = w & 1;
  const int lrow = lane >> 2;
  const int lcol = (lane & 3) * 8;
  const float scale = 0.08838834764831845f;  // 1/sqrt(128)

  floatx4 acc[4][4];
#pragma unroll
  for (int mt = 0; mt < 4; ++mt)
#pragma unroll
    for (int nt = 0; nt < 4; ++nt) acc[mt][nt] = (floatx4){0.f, 0.f, 0.f, 0.f};

  for (int k0 = 0; k0 < 128; k0 += 64) {
    __syncthreads();
#pragma unroll
    for (int c = w; c < 16; c += 4) {
      int s = c >> 3, r = (c & 7) * 16;
      gll16(Q + (size_t)(bm0 + r + lrow) * 128 + k0 + s * 32 + lcol, &As[s][r][0]);
    }
#pragma unroll
    for (int c = w; c < 16; c += 4) {
      int s = c >> 3, r = (c & 7) * 16;
      gll16(U + (size_t)(bn0 + r + lrow) * 128 + k0 + s * 32 + lcol, &Bs[s][r][0]);
    }
    __syncthreads();
#pragma unroll
    for (int s = 0; s < 2; ++s) {
      bf16x8 af[4], bfr[4];
#pragma unroll
      for (int mt = 0; mt < 4; ++mt)
        af[mt] = *(const bf16x8*)&As[s][wr * 64 + mt * 16 + l16][quad * 8];
#pragma unroll
      for (int nt = 0; nt < 4; ++nt)
        bfr[nt] = *(const bf16x8*)&Bs[s][wc * 64 + nt * 16 + l16][quad * 8];
#pragma unroll
      for (int mt = 0; mt < 4; ++mt)
#pragma unroll
        for (int nt = 0; nt < 4; ++nt)
          acc[mt][nt] =
              __builtin_amdgcn_mfma_f32_16x16x32_bf16(af[mt], bfr[nt], acc[mt][nt], 0, 0, 0);
    }
  }

  // Epilogue: exp, row-sum, store P (bf16).
  float rs[4][4];
#pragma unroll
  for (int mt = 0; mt < 4; ++mt)
#pragma unroll
    for (int r = 0; r < 4; ++r) rs[mt][r] = 0.f;

#pragma unroll
  for (int mt = 0; mt < 4; ++mt) {
    const int row0 = bm0 + wr * 64 + mt * 16 + quad * 4;
#pragma unroll
    for (int nt = 0; nt < 4; ++nt) {
      const int col = bn0 + wc * 64 + nt * 16 + l16;
#pragma unroll
      for (int r = 0; r < 4; ++r) {
        float p = __expf(acc[mt][nt][r] * scale);
        rs[mt][r] += p;
        P[(size_t)(row0 + r) * 4096 + col] = (__bf16)p;
      }
    }
  }
  // reduce rs across the 16 column-lanes (l16); lanes 0/16/32/48 hold results.
#pragma unroll
  for (int mt = 0; mt < 4; ++mt)
#pragma unroll
    for (int r = 0; r < 4; ++r) {
      float v = rs[mt][r];
      v += __shfl_xor(v, 1);
      v += __shfl_xor(v, 2);
      v += __shfl_xor(v, 4);
      v += __shfl_xor(v, 8);
      rs[mt][r] = v;
    }
  if (l16 == 0) {
    const int slot = blockIdx.x * 2 + wc;
#pragma unroll
    for (int mt = 0; mt < 4; ++mt) {
      const int row0 = bm0 + wr * 64 + mt * 16 + quad * 4;
#pragma unroll
      for (int r = 0; r < 4; ++r) lp[(size_t)(row0 + r) * 64 + slot] = rs[mt][r];
    }
  }
}

// ---------------------------------------------------------------------------
// PV GEMM, split-K=16: Op[z][q][d] = bf16( sum_{k in split z} P[q][k]*Ut[d][k] )
// BM=128, BN=128(=all of D), kPerSplit=256. grid (32 q-tiles, 16 splits).
// ---------------------------------------------------------------------------
__global__ __launch_bounds__(256) void pv_gemm(const __bf16* __restrict__ P,
                                               const __bf16* __restrict__ Ut,
                                               __bf16* __restrict__ Op) {
  __shared__ __bf16 As[2][128][32];
  __shared__ __bf16 Bs[2][128][32];
  const int bm0 = blockIdx.x * 128;
  const int z   = blockIdx.y;
  const int tid  = threadIdx.x;
  const int w    = tid >> 6;
  const int lane = tid & 63;
  const int quad = lane >> 4;
  const int l16  = lane & 15;
  const int wr   = w >> 1;
  const int wc   = w & 1;
  const int lrow = lane >> 2;
  const int lcol = (lane & 3) * 8;

  floatx4 acc[4][4];
#pragma unroll
  for (int mt = 0; mt < 4; ++mt)
#pragma unroll
    for (int nt = 0; nt < 4; ++nt) acc[mt][nt] = (floatx4){0.f, 0.f, 0.f, 0.f};

  const int kbeg = z * 256;
  for (int k0 = kbeg; k0 < kbeg + 256; k0 += 64) {
    __syncthreads();
#pragma unroll
    for (int c = w; c < 16; c += 4) {
      int s = c >> 3, r = (c & 7) * 16;
      gll16(P + (size_t)(bm0 + r + lrow) * 4096 + k0 + s * 32 + lcol, &As[s][r][0]);
    }
#pragma unroll
    for (int c = w; c < 16; c += 4) {
      int s = c >> 3, r = (c & 7) * 16;
      gll16(Ut + (size_t)(r + lrow) * 4096 + k0 + s * 32 + lcol, &Bs[s][r][0]);
    }
    __syncthreads();
#pragma unroll
    for (int s = 0; s < 2; ++s) {
      bf16x8 af[4], bfr[4];
#pragma unroll
      for (int mt = 0; mt < 4; ++mt)
        af[mt] = *(const bf16x8*)&As[s][wr * 64 + mt * 16 + l16][quad * 8];
#pragma unroll
      for (int nt = 0; nt < 4; ++nt)
        bfr[nt] = *(const bf16x8*)&Bs[s][wc * 64 + nt * 16 + l16][quad * 8];
#pragma unroll
      for (int mt = 0; mt < 4; ++mt)
#pragma unroll
        for (int nt = 0; nt < 4; ++nt)
          acc[mt][nt] =
              __builtin_amdgcn_mfma_f32_16x16x32_bf16(af[mt], bfr[nt], acc[mt][nt], 0, 0, 0);
    }
  }

  __bf16* Ob = Op + (size_t)z * 4096 * 128;
#pragma unroll
  for (int mt = 0; mt < 4; ++mt) {
    const int row0 = bm0 + wr * 64 + mt * 16 + quad * 4;
#pragma unroll
    for (int nt = 0; nt < 4; ++nt) {
      const int col = wc * 64 + nt * 16 + l16;
#pragma unroll
      for (int r = 0; r < 4; ++r) {
        Ob[(size_t)(row0 + r) * 128 + col] = (__bf16)acc[mt][nt][r];
      }
    }
  }
}

// ---------------------------------------------------------------------------
// Combine: out[q][d] = (sum_z Op[z][q][d]) / (sum_j lp[q][j]). 8 elems/thread.
// ---------------------------------------------------------------------------
__global__ __launch_bounds__(256) void combine_kernel(const __bf16* __restrict__ Op,
                                                      const float* __restrict__ lp,
                                                      float* __restrict__ out) {
  const int i = (blockIdx.x * 256 + threadIdx.x) * 8;  // 0 .. 524287 step 8
  const int row = i >> 7;
  float num[8] = {0.f, 0.f, 0.f, 0.f, 0.f, 0.f, 0.f, 0.f};
#pragma unroll
  for (int s = 0; s < 16; ++s) {
    bf16x8 v = *(const bf16x8*)(Op + (size_t)s * 524288 + i);
#pragma unroll
    for (int j = 0; j < 8; ++j) num[j] += (float)v[j];
  }
  float den = 0.f;
#pragma unroll
  for (int j = 0; j < 16; ++j) {
    float4 d4 = *(const float4*)(lp + (size_t)row * 64 + j * 4);
    den += d4.x + d4.y + d4.z + d4.w;
  }
  float inv = 1.f / den;
  float4 r0 = {num[0] * inv, num[1] * inv, num[2] * inv, num[3] * inv};
  float4 r1 = {num[4] * inv, num[5] * inv, num[6] * inv, num[7] * inv};
  *(float4*)(out + i) = r0;
  *(float4*)(out + i + 4) = r1;
}

extern "C" void kernel_launch(void* const* d_in, const int* in_sizes, int n_in,
                              void* d_out, int out_size, void* d_ws, size_t ws_size,
                              hipStream_t stream) {
  (void)in_sizes; (void)n_in; (void)out_size; (void)ws_size;
  const float* ctx      = (const float*)d_in[0];  // [4096,1024]
  const float* ent_embs = (const float*)d_in[1];  // [24636,128]
  const float* W1       = (const float*)d_in[2];  // [768,1024]
  const float* W2       = (const float*)d_in[3];  // [512,768]
  const float* W3       = (const float*)d_in[4];  // [128,512]
  const int*   ent_list = (const int*)d_in[5];    // [4096,50]
  float* out = (float*)d_out;

  // ws layout; peak use 80 MB (ws is 256 MB).
  char* base = (char*)d_ws;
  __bf16* user_n = (__bf16*)(base);                       // 1 MB
  __bf16* user_t = (__bf16*)(base + (1ull << 20));        // 1 MB
  __bf16* qb     = (__bf16*)(base + (2ull << 20));        // 1 MB
  float*  lp     = (float*)(base + (3ull << 20));         // 1 MB  [4096][64]
  __bf16* ctxb   = (__bf16*)(base + (4ull << 20));        // 8 MB
  __bf16* W1b    = (__bf16*)(base + (12ull << 20));       // 1.5 MB
  __bf16* W2b    = (__bf16*)(base + 14155776ull);         // 13.5 MB, 0.75 MB
  __bf16* W3b    = (__bf16*)(base + 14942208ull);         // 14.25 MB, 128 KB
  __bf16* x1b    = (__bf16*)(base + (15ull << 20));       // 6 MB
  __bf16* x2b    = (__bf16*)(base + (21ull << 20));       // 4 MB
  __bf16* O_part = (__bf16*)(base + (25ull << 20));       // 16 MB (bf16 x 16 splits)
  __bf16* Pm     = (__bf16*)(base + (48ull << 20));       // 32 MB  P matrix

  prep_kernel<<<3680, 256, 0, stream>>>(ctx, ctxb, W1, W1b, W2, W2b, W3, W3b,
                                        ent_embs, ent_list, user_n);
  transpose_kernel<<<dim3(64, 2), 256, 0, stream>>>(user_n, user_t);

  // MLP: 128x96 / 128x64 / 32x64 tiles, relu+cvt fused in epilogue.
  gemm_bt<4, 1, 2, 6, 1><<<dim3(8, 32), 256, 0, stream>>>(ctxb, W1b, x1b, 4096, 768, 1024);
  gemm_bt<4, 1, 2, 4, 1><<<dim3(8, 32), 256, 0, stream>>>(x1b, W2b, x2b, 4096, 512, 768);
  gemm_bt<2, 2, 1, 2, 0><<<dim3(2, 128), 256, 0, stream>>>(x2b, W3b, qb, 4096, 128, 512);

  // Attention: P = exp(Q U^T scale) (+row sums), O = P U via split-K, combine.
  sgemm_exp<<<dim3(32, 32), 256, 0, stream>>>(qb, user_n, Pm, lp);
  pv_gemm<<<dim3(32, 16), 256, 0, stream>>>(Pm, user_t, O_part);
  combine_kernel<<<256, 256, 0, stream>>>(O_part, lp, out);
}

// Round 8
// 169.555 us; speedup vs baseline: 1.0628x; 1.0111x over previous
//
#include <hip/hip_runtime.h>
#include <hip/hip_bf16.h>

#define SENTINEL 24635

using bf16x8  = __attribute__((ext_vector_type(8))) __bf16;
using bf16x2  = __attribute__((ext_vector_type(2))) __bf16;
using floatx4 = __attribute__((ext_vector_type(4))) float;

__device__ inline bf16x8 cvt8(float4 a, float4 b) {
  bf16x8 v;
  v[0] = (__bf16)a.x; v[1] = (__bf16)a.y; v[2] = (__bf16)a.z; v[3] = (__bf16)a.w;
  v[4] = (__bf16)b.x; v[5] = (__bf16)b.y; v[6] = (__bf16)b.z; v[7] = (__bf16)b.w;
  return v;
}

// async global->LDS, 16 B per lane. LDS dest = wave-uniform base + lane*16.
__device__ inline void gll16(const __bf16* g, __bf16* l) {
  __builtin_amdgcn_global_load_lds(
      (const __attribute__((address_space(1))) unsigned int*)g,
      (__attribute__((address_space(3))) unsigned int*)l, 16, 0, 0);
}

// ---------------------------------------------------------------------------
// Prep: f32->bf16 convert of ctx/W1/W2/W3 (blocks 0..2655, 8 elems/thread)
// fused with pool (blocks 2656..3679): user_n[b] = bf16 masked mean of
// ent_embs[ent_list[b,:cnt]]; cnt = first-SENTINEL prefix; cnt==0 -> sentinel.
// ---------------------------------------------------------------------------
__global__ __launch_bounds__(256) void prep_kernel(
    const float* __restrict__ s0, __bf16* __restrict__ d0,
    const float* __restrict__ s1, __bf16* __restrict__ d1,
    const float* __restrict__ s2, __bf16* __restrict__ d2,
    const float* __restrict__ s3, __bf16* __restrict__ d3,
    const float* __restrict__ ent, const int* __restrict__ ent_list,
    __bf16* __restrict__ user_n) {
  if (blockIdx.x < 2656) {
    // sizes in 8-elem units: ctx 524288, W1 98304, W2 49152, W3 8192
    int g = blockIdx.x * 256 + threadIdx.x;
    const float* s; __bf16* d; int i;
    if (g < 524288)               { s = s0; d = d0; i = g; }
    else if (g < 622592)          { s = s1; d = d1; i = g - 524288; }
    else if (g < 671744)          { s = s2; d = d2; i = g - 622592; }
    else if (g < 679936)          { s = s3; d = d3; i = g - 671744; }
    else return;
    i *= 8;
    float4 a = *(const float4*)(s + i);
    float4 b = *(const float4*)(s + i + 4);
    *(bf16x8*)(d + i) = cvt8(a, b);
    return;
  }
  const int b = (blockIdx.x - 2656) * 4 + (threadIdx.x >> 6);
  const int lane = threadIdx.x & 63;
  int myidx = (lane < 50) ? ent_list[b * 50 + lane] : 0;
  unsigned long long m = __ballot(lane < 50 && myidx == SENTINEL);
  const int cnt = (m == 0) ? 50 : (int)__builtin_ctzll(m);

  float sx = 0.f, sy = 0.f;
  for (int l0 = 0; l0 < 50; l0 += 10) {
    if (l0 >= cnt) break;  // wave-uniform
    float2 e[10];
#pragma unroll
    for (int j = 0; j < 10; ++j) {
      int idx = __shfl(myidx, l0 + j);
      e[j] = *(const float2*)(ent + (size_t)idx * 128 + lane * 2);
    }
#pragma unroll
    for (int j = 0; j < 10; ++j) {
      if (l0 + j < cnt) { sx += e[j].x; sy += e[j].y; }
    }
  }
  float vx, vy;
  if (cnt == 0) {
    float2 e = *(const float2*)(ent + (size_t)SENTINEL * 128 + lane * 2);
    vx = e.x; vy = e.y;
  } else {
    float inv = 1.f / (float)cnt;
    vx = sx * inv; vy = sy * inv;
  }
  bf16x2 o; o[0] = (__bf16)vx; o[1] = (__bf16)vy;
  *(bf16x2*)(user_n + (size_t)b * 128 + lane * 2) = o;
}

// ---------------------------------------------------------------------------
// GEMM device body: C[m][n] = bf16( act( sum_k A[m][k]*W[n][k] ) )
// A,W,C bf16 row-major (K contiguous). Block tile (WR*MT*16) x (WC*NT*16),
// BK=64, 256 threads = 4 waves WR x WC. LDS (caller-provided): two K-slabs
// of 32 (m97 layout: unpadded 64 B rows, gll16 chunks of 16 rows).
// ---------------------------------------------------------------------------
template <int WR, int WC, int MT, int NT, int RELU>
__device__ inline void gemm_body(const __bf16* __restrict__ A,
                                 const __bf16* __restrict__ W,
                                 __bf16* __restrict__ C,
                                 int M, int N, int K, int bn0, int bm0,
                                 char* lds) {
  constexpr int BM = WR * MT * 16;
  constexpr int BN = WC * NT * 16;
  auto As = (__bf16 (*)[BM][32])lds;                               // As[s][r][k]
  auto Bs = (__bf16 (*)[BN][32])(lds + (size_t)2 * BM * 32 * 2);   // Bs[s][r][k]
  const int tid  = threadIdx.x;
  const int w    = tid >> 6;
  const int lane = tid & 63;
  const int quad = lane >> 4;
  const int l16  = lane & 15;
  const int wr   = w / WC;
  const int wc   = w % WC;
  const int lrow = lane >> 2;        // 0..15 row within 1 KB chunk
  const int lcol = (lane & 3) * 8;   // bf16 col within 32-wide slab row

  floatx4 acc[MT][NT];
#pragma unroll
  for (int mt = 0; mt < MT; ++mt)
#pragma unroll
    for (int nt = 0; nt < NT; ++nt) acc[mt][nt] = (floatx4){0.f, 0.f, 0.f, 0.f};

  constexpr int nAc = 2 * (BM / 16);  // chunks: slab-major
  constexpr int nBc = 2 * (BN / 16);
  for (int k0 = 0; k0 < K; k0 += 64) {
    __syncthreads();
#pragma unroll
    for (int c = w; c < nAc; c += 4) {
      int s = c / (BM / 16);
      int r = (c % (BM / 16)) * 16;
      gll16(A + (size_t)(bm0 + r + lrow) * K + k0 + s * 32 + lcol, &As[s][r][0]);
    }
#pragma unroll
    for (int c = w; c < nBc; c += 4) {
      int s = c / (BN / 16);
      int r = (c % (BN / 16)) * 16;
      gll16(W + (size_t)(bn0 + r + lrow) * K + k0 + s * 32 + lcol, &Bs[s][r][0]);
    }
    __syncthreads();
#pragma unroll
    for (int s = 0; s < 2; ++s) {
      bf16x8 af[MT], bfr[NT];
#pragma unroll
      for (int mt = 0; mt < MT; ++mt)
        af[mt] = *(const bf16x8*)&As[s][wr * (MT * 16) + mt * 16 + l16][quad * 8];
#pragma unroll
      for (int nt = 0; nt < NT; ++nt)
        bfr[nt] = *(const bf16x8*)&Bs[s][wc * (NT * 16) + nt * 16 + l16][quad * 8];
#pragma unroll
      for (int mt = 0; mt < MT; ++mt)
#pragma unroll
        for (int nt = 0; nt < NT; ++nt)
          acc[mt][nt] =
              __builtin_amdgcn_mfma_f32_16x16x32_bf16(af[mt], bfr[nt], acc[mt][nt], 0, 0, 0);
    }
  }

#pragma unroll
  for (int mt = 0; mt < MT; ++mt) {
    const int row0 = bm0 + wr * (MT * 16) + mt * 16 + quad * 4;
#pragma unroll
    for (int nt = 0; nt < NT; ++nt) {
      const int col = bn0 + wc * (NT * 16) + nt * 16 + l16;
#pragma unroll
      for (int r = 0; r < 4; ++r) {
        float v = acc[mt][nt][r];
        if (RELU) v = fmaxf(v, 0.f);
        C[(size_t)(row0 + r) * N + col] = (__bf16)v;
      }
    }
  }
}

template <int WR, int WC, int MT, int NT, int RELU>
__global__ __launch_bounds__(256) void gemm_bt(const __bf16* __restrict__ A,
                                               const __bf16* __restrict__ W,
                                               __bf16* __restrict__ C,
                                               int M, int N, int K) {
  __shared__ char lds[(size_t)2 * ((WR * MT * 16) + (WC * NT * 16)) * 32 * 2];
  gemm_body<WR, WC, MT, NT, RELU>(A, W, C, M, N, K,
                                  blockIdx.x * (WC * NT * 16),
                                  blockIdx.y * (WR * MT * 16), lds);
}

// ---------------------------------------------------------------------------
// gemm1 (64x64 tiles, grid part 0..767 = (12 n)x(64 m)) fused with the
// user_n -> user_t transpose (blocks 768..895, 64x64 bf16 tiles via LDS).
// Both consume prep outputs only; mutually independent.
// ---------------------------------------------------------------------------
__global__ __launch_bounds__(256) void gemm1_tr(const __bf16* __restrict__ A,
                                                const __bf16* __restrict__ W,
                                                __bf16* __restrict__ C,
                                                const __bf16* __restrict__ un,
                                                __bf16* __restrict__ ut) {
  __shared__ char lds[16384];
  const int bx = blockIdx.x;
  if (bx < 768) {
    gemm_body<2, 2, 2, 2, 1>(A, W, C, 4096, 768, 1024,
                             (bx % 12) * 64, (bx / 12) * 64, lds);
    return;
  }
  const int idx = bx - 768;             // 0..127
  const int r0 = (idx & 63) * 64;       // key rows
  const int c0 = (idx >> 6) * 64;       // dim cols
  auto T = (__bf16 (*)[72])lds;
  const int tid = threadIdx.x;
#pragma unroll
  for (int p = 0; p < 2; ++p) {
    int r = (tid >> 3) + p * 32;
    int c = (tid & 7) * 8;
    *(bf16x8*)&T[r][c] = *(const bf16x8*)(un + (size_t)(r0 + r) * 128 + c0 + c);
  }
  __syncthreads();
#pragma unroll
  for (int p = 0; p < 2; ++p) {
    int c = (tid >> 3) + p * 32;
    int r = (tid & 7) * 8;
    bf16x8 v;
#pragma unroll
    for (int j = 0; j < 8; ++j) v[j] = T[r + j][c];
    *(bf16x8*)(ut + (size_t)(c0 + c) * 4096 + r0 + r) = v;
  }
}

// ---------------------------------------------------------------------------
// Flash attention, LDS-staged (R5 structure), no max-subtraction
// (|scores| ~ 1e-2, exp safe):
//   O_part[split] = sum_chunks exp(Q Uc^T * scale) @ Uc ; lp[q][split] = row sums
// 64 q-rows/block (wave owns 16); grid (64 q-tiles, 16 key-splits) = 1024
// blocks; LDS 45 KB -> 3 blocks/CU. 4 chunks of 64 keys per split;
// 2 barriers/chunk (Ps is wave-private: no barrier).
// ---------------------------------------------------------------------------
__global__ __launch_bounds__(256) void flash_attn(const __bf16* __restrict__ Q,
                                                  const __bf16* __restrict__ Un_g,
                                                  const __bf16* __restrict__ Ut_g,
                                                  __bf16* __restrict__ O_part,
                                                  float* __restrict__ lp) {
  __shared__ __bf16 Un[64][136];    // [key][d]   stride 272 B (2-way banks)
  __shared__ __bf16 Ut[128][72];    // [d][key]   stride 144 B
  __shared__ __bf16 Ps[4][16][72];  // per-wave P [qrow][key]
  const int tid  = threadIdx.x;
  const int w    = tid >> 6;
  const int lane = tid & 63;
  const int quad = lane >> 4;
  const int l16  = lane & 15;
  const int qrow0 = blockIdx.x * 64;
  const int split = blockIdx.y;
  const float scale = 0.08838834764831845f;  // 1/sqrt(128)

  bf16x8 aq[4];
#pragma unroll
  for (int c = 0; c < 4; ++c)
    aq[c] = *(const bf16x8*)(Q + (size_t)(qrow0 + w * 16 + l16) * 128 + c * 32 + quad * 8);

  floatx4 o[8];
#pragma unroll
  for (int t = 0; t < 8; ++t) o[t] = (floatx4){0.f, 0.f, 0.f, 0.f};
  float lsum[4] = {0.f, 0.f, 0.f, 0.f};

  for (int chunk = 0; chunk < 4; ++chunk) {
    const int key0 = split * 256 + chunk * 64;
    __syncthreads();  // staged buffers safe to overwrite
#pragma unroll
    for (int p = 0; p < 4; ++p) {
      int r = (tid >> 4) + p * 16;
      int c = (tid & 15) * 8;
      *(bf16x8*)&Un[r][c] = *(const bf16x8*)(Un_g + (size_t)(key0 + r) * 128 + c);
    }
#pragma unroll
    for (int p = 0; p < 4; ++p) {
      int d = (tid >> 3) + p * 32;
      int kk = (tid & 7) * 8;
      *(bf16x8*)&Ut[d][kk] = *(const bf16x8*)(Ut_g + (size_t)d * 4096 + key0 + kk);
    }
    __syncthreads();

    // S = Q Uc^T (C-layout), exp fp32, P -> wave-private LDS (bf16), row sums.
#pragma unroll
    for (int t = 0; t < 4; ++t) {
      floatx4 s = (floatx4){0.f, 0.f, 0.f, 0.f};
#pragma unroll
      for (int c = 0; c < 4; ++c) {
        bf16x8 bk = *(const bf16x8*)&Un[t * 16 + l16][c * 32 + quad * 8];
        s = __builtin_amdgcn_mfma_f32_16x16x32_bf16(aq[c], bk, s, 0, 0, 0);
      }
#pragma unroll
      for (int r = 0; r < 4; ++r) {
        float pv = __expf(s[r] * scale);
        lsum[r] += pv;
        Ps[w][quad * 4 + r][t * 16 + l16] = (__bf16)pv;
      }
    }
    // Ps is wave-private: compiler lgkmcnt ordering suffices, no barrier.

    // O += P @ Uc
#pragma unroll
    for (int c2 = 0; c2 < 2; ++c2) {
      bf16x8 ap = *(const bf16x8*)&Ps[w][l16][c2 * 32 + quad * 8];
#pragma unroll
      for (int dt = 0; dt < 8; ++dt) {
        bf16x8 bv = *(const bf16x8*)&Ut[dt * 16 + l16][c2 * 32 + quad * 8];
        o[dt] = __builtin_amdgcn_mfma_f32_16x16x32_bf16(ap, bv, o[dt], 0, 0, 0);
      }
    }
  }

  // Row sums: reduce over the 16 key-columns held across l16 (stays in quad).
#pragma unroll
  for (int r = 0; r < 4; ++r) {
    float v = lsum[r];
    v += __shfl_xor(v, 1);
    v += __shfl_xor(v, 2);
    v += __shfl_xor(v, 4);
    v += __shfl_xor(v, 8);
    lsum[r] = v;
  }

  __bf16* Ob = O_part + (size_t)split * 4096 * 128;
  const int row0 = qrow0 + w * 16 + quad * 4;
#pragma unroll
  for (int dt = 0; dt < 8; ++dt) {
#pragma unroll
    for (int r = 0; r < 4; ++r) {
      Ob[(size_t)(row0 + r) * 128 + dt * 16 + l16] = (__bf16)o[dt][r];
    }
  }
  if (l16 == 0) {
#pragma unroll
    for (int r = 0; r < 4; ++r) lp[(size_t)(row0 + r) * 16 + split] = lsum[r];
  }
}

// ---------------------------------------------------------------------------
// Combine 16 key-splits: out = (sum_s O_s) / (sum_s lp[row][s]). 8 elems/thr.
// ---------------------------------------------------------------------------
__global__ __launch_bounds__(256) void combine_kernel(const __bf16* __restrict__ Op,
                                                      const float* __restrict__ lp,
                                                      float* __restrict__ out) {
  const int i = (blockIdx.x * 256 + threadIdx.x) * 8;  // 0 .. 524287 step 8
  const int row = i >> 7;
  float num[8] = {0.f, 0.f, 0.f, 0.f, 0.f, 0.f, 0.f, 0.f};
#pragma unroll
  for (int s = 0; s < 16; ++s) {
    bf16x8 v = *(const bf16x8*)(Op + (size_t)s * 524288 + i);
#pragma unroll
    for (int j = 0; j < 8; ++j) num[j] += (float)v[j];
  }
  float den = 0.f;
#pragma unroll
  for (int j = 0; j < 4; ++j) {
    float4 d4 = *(const float4*)(lp + (size_t)row * 16 + j * 4);
    den += d4.x + d4.y + d4.z + d4.w;
  }
  float inv = 1.f / den;
  float4 r0 = {num[0] * inv, num[1] * inv, num[2] * inv, num[3] * inv};
  float4 r1 = {num[4] * inv, num[5] * inv, num[6] * inv, num[7] * inv};
  *(float4*)(out + i) = r0;
  *(float4*)(out + i + 4) = r1;
}

extern "C" void kernel_launch(void* const* d_in, const int* in_sizes, int n_in,
                              void* d_out, int out_size, void* d_ws, size_t ws_size,
                              hipStream_t stream) {
  (void)in_sizes; (void)n_in; (void)out_size; (void)ws_size;
  const float* ctx      = (const float*)d_in[0];  // [4096,1024]
  const float* ent_embs = (const float*)d_in[1];  // [24636,128]
  const float* W1       = (const float*)d_in[2];  // [768,1024]
  const float* W2       = (const float*)d_in[3];  // [512,768]
  const float* W3       = (const float*)d_in[4];  // [128,512]
  const int*   ent_list = (const int*)d_in[5];    // [4096,50]
  float* out = (float*)d_out;

  // ws layout; peak use 41 MB (ws is 256 MB).
  char* base = (char*)d_ws;
  __bf16* user_n = (__bf16*)(base);                       // 1 MB
  __bf16* user_t = (__bf16*)(base + (1ull << 20));        // 1 MB
  __bf16* qb     = (__bf16*)(base + (2ull << 20));        // 1 MB
  float*  lp     = (float*)(base + (3ull << 20));         // 256 KB [4096][16]
  __bf16* ctxb   = (__bf16*)(base + (4ull << 20));        // 8 MB
  __bf16* W1b    = (__bf16*)(base + (12ull << 20));       // 1.5 MB
  __bf16* W2b    = (__bf16*)(base + 14155776ull);         // 13.5 MB, 0.75 MB
  __bf16* W3b    = (__bf16*)(base + 14942208ull);         // 14.25 MB, 128 KB
  __bf16* x1b    = (__bf16*)(base + (15ull << 20));       // 6 MB
  __bf16* x2b    = (__bf16*)(base + (21ull << 20));       // 4 MB
  __bf16* O_part = (__bf16*)(base + (25ull << 20));       // 16 MB (bf16 x 16)

  // 6 dispatches total.
  prep_kernel<<<3680, 256, 0, stream>>>(ctx, ctxb, W1, W1b, W2, W2b, W3, W3b,
                                        ent_embs, ent_list, user_n);
  gemm1_tr<<<896, 256, 0, stream>>>(ctxb, W1b, x1b, user_n, user_t);
  gemm_bt<2, 2, 2, 2, 1><<<dim3(8, 64), 256, 0, stream>>>(x1b, W2b, x2b, 4096, 512, 768);
  gemm_bt<2, 2, 1, 1, 0><<<dim3(4, 128), 256, 0, stream>>>(x2b, W3b, qb, 4096, 128, 512);
  flash_attn<<<dim3(64, 16), 256, 0, stream>>>(qb, user_n, user_t, O_part, lp);
  combine_kernel<<<256, 256, 0, stream>>>(O_part, lp, out);
}